// Round 16
// baseline (137.822 us; speedup 1.0000x reference)
//
#include <hip/hip_runtime.h>

#define BB 4
#define NN 2048
#define FF 128
#define NP 2176  // padded WhT row stride (shorts)
#define ALPHA 0.2f
#define SHIFT_C 16.0f  // exp(x-16): x=LR(f1+f2) bounded ~|10|; masked -> p=0 via bit-multiply

typedef short bf16x8 __attribute__((ext_vector_type(8)));
typedef float f32x4 __attribute__((ext_vector_type(4)));
typedef unsigned u32;

__device__ inline short f2bf(float f) {  // RNE float -> bf16 bits
    union { float f; unsigned u; } v; v.f = f;
    unsigned r = (v.u + 0x7FFFu + ((v.u >> 16) & 1u)) >> 16;
    return (short)r;
}
__device__ inline float bf2f(short s) {
    union { float f; unsigned u; } v;
    v.u = ((unsigned)(unsigned short)s) << 16;
    return v.f;
}

// async 16B global->LDS (gfx950); HW writes lds_base + lane*16
__device__ inline void cp16(const void* g, void* l) {
    __builtin_amdgcn_global_load_lds(
        (const __attribute__((address_space(1))) u32*)g,
        (__attribute__((address_space(3))) u32*)l, 16, 0, 0);
}

// ---------------------------------------------------------------------------
// k_wh: round-15 body (passed) MINUS the adj-pack phase (pure deletion).
// Fused f12 + fp32 GEMM + split-bf16 NP-strided store. 16 rows/block, grid 512.
// ---------------------------------------------------------------------------
__global__ __launch_bounds__(256) void k_wh(const float* __restrict__ h,
                                            const float* __restrict__ W,
                                            const float* __restrict__ a,
                                            short* __restrict__ WhHiT,
                                            short* __restrict__ WhLoT,
                                            float* __restrict__ f1,
                                            float* __restrict__ f2) {
    __shared__ float Wa[2 * FF];
    __shared__ float hs[16 * 128];  // 8 KB
    int tid = threadIdx.x;
    int r0 = blockIdx.x * 16;

    {
        int fin = tid & 127;
        const float* av = (tid < 128) ? a : (a + FF);
        const float* wr = W + (size_t)fin * FF;
        float s = 0.f;
        for (int o = 0; o < FF; o += 4) {
            float4 wv = *(const float4*)(wr + o);
            float4 avv = *(const float4*)(av + o);
            s += wv.x * avv.x + wv.y * avv.y + wv.z * avv.z + wv.w * avv.w;
        }
        Wa[(tid < 128 ? 0 : FF) + fin] = s;
    }
    {
        const float4* src = (const float4*)(h + (size_t)r0 * FF);
        float4* dst = (float4*)hs;
        dst[tid] = src[tid];
        dst[256 + tid] = src[256 + tid];
    }
    __syncthreads();

    {
        int w = tid >> 6, lane = tid & 63;
        float wa1_0 = Wa[lane], wa1_1 = Wa[lane + 64];
        float wa2_0 = Wa[FF + lane], wa2_1 = Wa[FF + lane + 64];
        for (int rr = 0; rr < 4; ++rr) {
            int rloc = w * 4 + rr;
            int row = r0 + rloc;
            float x0 = hs[rloc * FF + lane], x1 = hs[rloc * FF + lane + 64];
            float s1 = x0 * wa1_0 + x1 * wa1_1;
            float s2 = x0 * wa2_0 + x1 * wa2_1;
#pragma unroll
            for (int m = 32; m >= 1; m >>= 1) {
                s1 += __shfl_xor(s1, m, 64);
                s2 += __shfl_xor(s2, m, 64);
            }
            if (lane == 0) { f1[row] = s1; f2[row] = s2; }
        }
    }

    int f4 = (tid & 31) * 4;
    int rg = tid >> 5;  // 0..7
    float acc[2][4];
#pragma unroll
    for (int rr = 0; rr < 2; ++rr)
#pragma unroll
        for (int cc = 0; cc < 4; ++cc) acc[rr][cc] = 0.f;

    for (int k0 = 0; k0 < FF; k0 += 4) {
        float4 wv[4];
#pragma unroll
        for (int kk = 0; kk < 4; ++kk)
            wv[kk] = *(const float4*)(W + (size_t)(k0 + kk) * FF + f4);
        float4 hv[2];
#pragma unroll
        for (int rr = 0; rr < 2; ++rr)
            hv[rr] = *(const float4*)(hs + (rg * 2 + rr) * FF + k0);
#pragma unroll
        for (int rr = 0; rr < 2; ++rr) {
            float hk[4] = {hv[rr].x, hv[rr].y, hv[rr].z, hv[rr].w};
#pragma unroll
            for (int kk = 0; kk < 4; ++kk) {
                acc[rr][0] += hk[kk] * wv[kk].x;
                acc[rr][1] += hk[kk] * wv[kk].y;
                acc[rr][2] += hk[kk] * wv[kk].z;
                acc[rr][3] += hk[kk] * wv[kk].w;
            }
        }
    }
    int rloc = r0 + rg * 2;
    int b = rloc >> 11;
    int j = rloc & (NN - 1);  // even
#pragma unroll
    for (int cc = 0; cc < 4; ++cc) {
        float v0 = acc[0][cc], v1 = acc[1][cc];
        short h0 = f2bf(v0), h1 = f2bf(v1);
        short l0 = f2bf(v0 - bf2f(h0)), l1 = f2bf(v1 - bf2f(h1));
        size_t off = (size_t)(b * FF + f4 + cc) * NP + j;
        *(short2*)(WhHiT + off) = make_short2(h0, h1);
        *(short2*)(WhLoT + off) = make_short2(l0, l1);
    }
}

// ---------------------------------------------------------------------------
// k_attn flash-v6: round-15 structure VERBATIM except the adj-bitmask loads
// are replaced by direct int2 adj reads in the same period-ahead prefetch
// slots (v>0 replaces bit-extract; math bit-identical). adjp/k_pack deleted.
// ---------------------------------------------------------------------------
__global__ __launch_bounds__(512, 4) void k_attn(const short* __restrict__ WhHiT,
                                                 const short* __restrict__ WhLoT,
                                                 const int* __restrict__ adj,
                                                 const float* __restrict__ f1,
                                                 const float* __restrict__ f2,
                                                 float* __restrict__ out) {
    __shared__ __align__(16) char lds[44160];
    char* Bb = lds;                           // 4 x 8192 (per step-buf: hi 4K + lo 4K)
    char* Ab = lds + 32768;                   // 4 x 2560
    float* row_ps = (float*)(lds + 43008);    // [8][32]
    float* row_inv = (float*)(lds + 44032);   // [32]

    int tid = threadIdx.x;
    int w = tid >> 6, lane = tid & 63;        // w 0..7
    int blk = blockIdx.x;
    int b = blk >> 7;
    int tile = (blk >> 1) & 63;
    int half = blk & 1;
    int i0 = tile * 32;

    int r_a = lane & 15, kg = lane >> 4;
    int mi = w >> 2, ni = w & 3;

    // A-build role: thread -> (row rb, j-pair jp); all 512 threads
    int rb = tid & 31;
    int jp = (tid >> 5) & 15;
    float f1i = f1[b * NN + i0 + rb];
    const int* adjrow = adj + (size_t)(i0 + rb) * NN;
    const float* f2b = f2 + b * NN;
    int aoff = (rb >> 4) * 1280 + (rb & 15) * 80 + jp * 4;

    // B-stage role: waves 0-3 hi, 4-7 lo; 16 fo each within block's half
    int isLo = w >> 2;
    int sub = w & 3;
    int fo_s = half * 64 + sub * 16 + (lane >> 2);
    int oc_s = lane & 3;
    const short* gB = (isLo ? WhLoT : WhHiT) + (size_t)(b * FF + fo_s) * NP + oc_s * 8;
    int bB = isLo * 4096 + sub * 1024;  // wave-uniform base within one 8KB step-buf

    f32x4 acc = {0.f, 0.f, 0.f, 0.f};
    float sp = 0.f;

    // ---- prologue: stage+build period 0; prefetch period-1 regs ----
    cp16(gB, Bb + bB);
    cp16(gB + 32, Bb + 8192 + bB);
    {
        float2 qa = *(const float2*)(f2b + jp * 2);
        float2 qb = *(const float2*)(f2b + 32 + jp * 2);
        int2 ma = *(const int2*)(adjrow + jp * 2);
        int2 mb = *(const int2*)(adjrow + 32 + jp * 2);
        float x;
        x = f1i + qa.x; x = fmaxf(x, ALPHA * x);
        float p00 = __expf(x - SHIFT_C) * (float)(ma.x > 0);
        x = f1i + qa.y; x = fmaxf(x, ALPHA * x);
        float p01 = __expf(x - SHIFT_C) * (float)(ma.y > 0);
        x = f1i + qb.x; x = fmaxf(x, ALPHA * x);
        float p10 = __expf(x - SHIFT_C) * (float)(mb.x > 0);
        x = f1i + qb.y; x = fmaxf(x, ALPHA * x);
        float p11 = __expf(x - SHIFT_C) * (float)(mb.y > 0);
        sp += p00 + p01 + p10 + p11;
        union { float f; u32 u; } u0, u1;
        u0.f = p00; u1.f = p01;
        *(u32*)(Ab + aoff) = ((u0.u + 0x8000u) >> 16) | (((u1.u + 0x8000u) >> 16) << 16);
        u0.f = p10; u1.f = p11;
        *(u32*)(Ab + 2560 + aoff) = ((u0.u + 0x8000u) >> 16) | (((u1.u + 0x8000u) >> 16) << 16);
    }
    float2 pfa = *(const float2*)(f2b + 64 + jp * 2);
    float2 pfb = *(const float2*)(f2b + 96 + jp * 2);
    int2 pma = *(const int2*)(adjrow + 64 + jp * 2);
    int2 pmb = *(const int2*)(adjrow + 96 + jp * 2);
    __syncthreads();

    for (int p = 0; p < 32; ++p) {
        int par = p & 1, opar = par ^ 1;
        // stage B for period p+1 (wrapped at p=31; wrap unread)
        {
            int j0n = ((2 * p + 2) & 63) * 32;
            int j1n = ((2 * p + 3) & 63) * 32;
            cp16(gB + j0n, Bb + opar * 16384 + bB);
            cp16(gB + j1n, Bb + opar * 16384 + 8192 + bB);
        }
        // build A for period p+1 from prefetched regs
        {
            float x;
            x = f1i + pfa.x; x = fmaxf(x, ALPHA * x);
            float p00 = __expf(x - SHIFT_C) * (float)(pma.x > 0);
            x = f1i + pfa.y; x = fmaxf(x, ALPHA * x);
            float p01 = __expf(x - SHIFT_C) * (float)(pma.y > 0);
            x = f1i + pfb.x; x = fmaxf(x, ALPHA * x);
            float p10 = __expf(x - SHIFT_C) * (float)(pmb.x > 0);
            x = f1i + pfb.y; x = fmaxf(x, ALPHA * x);
            float p11 = __expf(x - SHIFT_C) * (float)(pmb.y > 0);
            if (p < 31) sp += p00 + p01 + p10 + p11;  // exclude wrapped rebuild
            union { float f; u32 u; } u0, u1;
            u0.f = p00; u1.f = p01;
            *(u32*)(Ab + opar * 5120 + aoff) =
                ((u0.u + 0x8000u) >> 16) | (((u1.u + 0x8000u) >> 16) << 16);
            u0.f = p10; u1.f = p11;
            *(u32*)(Ab + opar * 5120 + 2560 + aoff) =
                ((u0.u + 0x8000u) >> 16) | (((u1.u + 0x8000u) >> 16) << 16);
        }
        // prefetch regs for period p+2 (wrapped)
        {
            int s0 = (2 * p + 4) & 63, s1 = (2 * p + 5) & 63;
            pfa = *(const float2*)(f2b + s0 * 32 + jp * 2);
            pfb = *(const float2*)(f2b + s1 * 32 + jp * 2);
            pma = *(const int2*)(adjrow + s0 * 32 + jp * 2);
            pmb = *(const int2*)(adjrow + s1 * 32 + jp * 2);
        }
        // compute steps 2p, 2p+1 from parity-own buffers
        {
            char* bbase = Bb + par * 16384;
            char* abase = Ab + par * 5120;
            int boff = (ni * 16 + r_a) * 64 + kg * 16;
            bf16x8 af0 = *(const bf16x8*)(abase + mi * 1280 + r_a * 80 + kg * 16);
            bf16x8 b0h = *(const bf16x8*)(bbase + boff);
            bf16x8 b0l = *(const bf16x8*)(bbase + 4096 + boff);
            acc = __builtin_amdgcn_mfma_f32_16x16x32_bf16(af0, b0h, acc, 0, 0, 0);
            acc = __builtin_amdgcn_mfma_f32_16x16x32_bf16(af0, b0l, acc, 0, 0, 0);
            bf16x8 af1 = *(const bf16x8*)(abase + 2560 + mi * 1280 + r_a * 80 + kg * 16);
            bf16x8 b1h = *(const bf16x8*)(bbase + 8192 + boff);
            bf16x8 b1l = *(const bf16x8*)(bbase + 8192 + 4096 + boff);
            acc = __builtin_amdgcn_mfma_f32_16x16x32_bf16(af1, b1h, acc, 0, 0, 0);
            acc = __builtin_amdgcn_mfma_f32_16x16x32_bf16(af1, b1l, acc, 0, 0, 0);
        }
        __syncthreads();
    }

    // ---- row sums ----
    sp += __shfl_xor(sp, 32, 64);              // jp 2w <-> 2w+1, same row rb
    if (lane < 32) row_ps[w * 32 + lane] = sp;
    __syncthreads();
    if (tid < 32) {
        float t = 0.f;
#pragma unroll
        for (int ww = 0; ww < 8; ++ww) t += row_ps[ww * 32 + tid];
        row_inv[tid] = 1.0f / t;
    }
    __syncthreads();

    // ---- direct normalized store: rows i0+mi*16+kg*4+q, col half*64+ni*16+r_a ----
    float* ob = out + ((size_t)b * NN + i0 + mi * 16) * FF + half * 64 + ni * 16;
#pragma unroll
    for (int q = 0; q < 4; ++q) {
        int rr = kg * 4 + q;
        ob[(size_t)rr * FF + r_a] = acc[q] * row_inv[mi * 16 + rr];
    }
}

// ---------------------------------------------------------------------------
extern "C" void kernel_launch(void* const* d_in, const int* in_sizes, int n_in,
                              void* d_out, int out_size, void* d_ws, size_t ws_size,
                              hipStream_t stream) {
    const float* h   = (const float*)d_in[0];
    const int*   adj = (const int*)d_in[1];
    const float* W   = (const float*)d_in[2];
    const float* a   = (const float*)d_in[3];
    float* out = (float*)d_out;

    short* WhHiT = (short*)d_ws;                          // 2.13 MB
    short* WhLoT = WhHiT + (size_t)BB * FF * NP;          // 2.13 MB
    float* f1 = (float*)(WhLoT + (size_t)BB * FF * NP);   // 32 KB
    float* f2 = f1 + (size_t)BB * NN;                     // 32 KB (total ~4.32 MB)

    k_wh<<<(BB * NN) / 16, 256, 0, stream>>>(h, W, a, WhHiT, WhLoT, f1, f2);
    k_attn<<<512, 512, 0, stream>>>(WhHiT, WhLoT, adj, f1, f2, out);
}